// Round 1
// 145.630 us; speedup vs baseline: 1.0576x; 1.0576x over previous
//
#include <hip/hip_runtime.h>

#define WIRES   12
#define NSTATE  4096          // 2^12
#define QDEPTH  8
#define BLOCK   256           // FOUR waves per block = one batch element
#define PER_T   16            // 4 local index bits; state in 32 VGPRs

using f2 = __attribute__((ext_vector_type(2))) float;

// Pitch-17 padded layout: amp a lives at f2-slot a + (a>>4)
// (rows of 16 f2, pitch 17). Affine in the local index k for every
// phase pattern -> ds addresses are base + compile-time immediate.
// Per-16-lane-group bank-pair coverage is complete for all three
// write/read patterns (W1: (g+k)%16, R1: (k+glo)%16, R2: (ghi+glo)%16).
__device__ __forceinline__ int slotf(int a) { return a + (a >> 4); }

// Column j of the GF(2)-linear CNOT-ring permutation of layer l:
// F = g_0∘g_1∘...∘g_11 (g_11 applied first / innermost).
constexpr int colF(int l, int j) {
    int rr = (l % (WIRES - 1)) + 1;
    int v = 1 << j;
    for (int k = WIRES - 1; k >= 0; --k) {
        int bc = 11 - k;                   // control bit
        int bt = 11 - ((k + rr) % WIRES);  // target bit
        v ^= ((v >> bc) & 1) << bt;
    }
    return v;
}
struct ColsT { int v[QDEPTH][WIRES]; };
constexpr ColsT mkCols() {
    ColsT c{};
    for (int l = 0; l < QDEPTH; ++l)
        for (int j = 0; j < WIRES; ++j) c.v[l][j] = colF(l, j);
    return c;
}
static __device__ const ColsT COLS = mkCols();   // rodata, uniform s_load

// ---- setup kernel: 96 rotation matrices -> d_ws (8 f2 per gate) ----
// Entries pre-expanded for packed math: urr = {re,re}, uw = {-im,+im}.
__global__ void mats_kernel(const float* __restrict__ wts, f2* __restrict__ mg)
{
    int t = blockIdx.x * blockDim.x + threadIdx.x;
    if (t >= QDEPTH * WIRES) return;
    float phi   = tanhf(wts[t * 3 + 0]);
    float theta = tanhf(wts[t * 3 + 1]);
    float omega = tanhf(wts[t * 3 + 2]);
    float c  = cosf(theta * 0.5f);
    float s  = sinf(theta * 0.5f);
    float a  = 0.5f * (phi + omega);
    float bm = 0.5f * (phi - omega);
    float ca = cosf(a),  sa = sinf(a);
    float cb = cosf(bm), sb = sinf(bm);
    // U00 = (c*ca, -c*sa)  U01 = (-s*cb, -s*sb)
    // U10 = (s*cb, -s*sb)  U11 = (c*ca,  c*sa)
    f2* m = mg + t * 8;
    m[0] = f2{ c * ca,  c * ca};   // u00 re,re
    m[1] = f2{ c * sa, -c * sa};   // {-im,+im}, im=-c*sa
    m[2] = f2{-s * cb, -s * cb};   // u01 re,re
    m[3] = f2{ s * sb, -s * sb};   // {-im,+im}, im=-s*sb
    m[4] = f2{ s * cb,  s * cb};   // u10 re,re
    m[5] = f2{ s * sb, -s * sb};   // {-im,+im}, im=-s*sb
    m[6] = f2{ c * ca,  c * ca};   // u11 re,re
    m[7] = f2{-c * sa,  c * sa};   // {-im,+im}, im=+c*sa
}

// 2x2 complex gate on local register bit P. ONE asm block per TWO pairs:
// four accumulator chains (a0,b0,a1,b1) issued round-robin so dependent
// pk-ops are 4 instructions (16 issue cycles at 4cy/pk) apart -> no
// latency stalls. Perp {-y,x} folded via op_sel.
template<int P>
__device__ __forceinline__ void gate(f2 r[PER_T], const f2* __restrict__ m)
{
    const f2 u00r = m[0], u00w = m[1], u01r = m[2], u01w = m[3];
    const f2 u10r = m[4], u10w = m[5], u11r = m[6], u11w = m[7];
    #pragma unroll
    for (int pr = 0; pr < PER_T / 2; pr += 2) {
        const int k0 = ((pr >> P) << (P + 1)) | (pr & ((1 << P) - 1));
        const int k1 = k0 | (1 << P);
        const int q  = pr + 1;
        const int j0 = ((q >> P) << (P + 1)) | (q & ((1 << P) - 1));
        const int j1 = j0 | (1 << P);
        f2 a0, b0, a1, b1;
        asm("v_pk_mul_f32 %0, %4, %8\n\t"
            "v_pk_mul_f32 %1, %4, %12\n\t"
            "v_pk_mul_f32 %2, %6, %8\n\t"
            "v_pk_mul_f32 %3, %6, %12\n\t"
            "v_pk_fma_f32 %0, %4, %9, %0 op_sel:[1,0,0] op_sel_hi:[0,1,1]\n\t"
            "v_pk_fma_f32 %1, %4, %13, %1 op_sel:[1,0,0] op_sel_hi:[0,1,1]\n\t"
            "v_pk_fma_f32 %2, %6, %9, %2 op_sel:[1,0,0] op_sel_hi:[0,1,1]\n\t"
            "v_pk_fma_f32 %3, %6, %13, %3 op_sel:[1,0,0] op_sel_hi:[0,1,1]\n\t"
            "v_pk_fma_f32 %0, %5, %10, %0\n\t"
            "v_pk_fma_f32 %1, %5, %14, %1\n\t"
            "v_pk_fma_f32 %2, %7, %10, %2\n\t"
            "v_pk_fma_f32 %3, %7, %14, %3\n\t"
            "v_pk_fma_f32 %0, %5, %11, %0 op_sel:[1,0,0] op_sel_hi:[0,1,1]\n\t"
            "v_pk_fma_f32 %1, %5, %15, %1 op_sel:[1,0,0] op_sel_hi:[0,1,1]\n\t"
            "v_pk_fma_f32 %2, %7, %11, %2 op_sel:[1,0,0] op_sel_hi:[0,1,1]\n\t"
            "v_pk_fma_f32 %3, %7, %15, %3 op_sel:[1,0,0] op_sel_hi:[0,1,1]"
            : "=&v"(a0), "=&v"(b0), "=&v"(a1), "=&v"(b1)
            : "v"(r[k0]), "v"(r[k1]), "v"(r[j0]), "v"(r[j1]),
              "v"(u00r), "v"(u00w), "v"(u01r), "v"(u01w),
              "v"(u10r), "v"(u10w), "v"(u11r), "v"(u11w));
        r[k0] = a0; r[k1] = b0; r[j0] = a1; r[j1] = b1;
    }
}

// FOUR waves = one batch element. g = threadIdx.x (8 bits).
// Canonical: r[k] = amp[(g<<4)|k]  (amp bit b <-> wire 11-b).
// Per layer, 3 phases of 4 wires each:
//   P1: wires 8..11 on amp bits 3..0 (k bits)
//   T1: local -> amp bits 7..4:  r[k] = amp[(ghi<<8)|(k<<4)|glo]
//   P2: wires 4..7
//   T2: local -> amp bits 11..8: r[k] = amp[(k<<8)|(ghi<<4)|glo]
//   P3: wires 0..3
//   T3: scatter + gather canonical ∘ F (CNOT ring folded in)
// Only 4 barriers/layer: R1's read-set == W2's write-set PER LANE
// (bijective amp<->lane map identical for both), so no barrier between
// a read round and the write round that returns to the same slots.
__global__ __launch_bounds__(BLOCK, 4) void qsim_kernel(
    const float* __restrict__ x,
    const f2*    __restrict__ mats_g,
    const int*   __restrict__ reps_ptr,
    float*       __restrict__ out,
    int write_mode)
{
    __shared__ f2 st[4352];                          // 34816 B -> 4 blocks/CU

    const int g   = threadIdx.x;
    const int b   = blockIdx.x;
    const int ghi = g >> 4, glo = g & 15;
    const int w1b = 17 * g;                // W1/R3-target base: slot(g<<4|k)=17g+k
    const int rb1 = 272 * ghi + glo;       // R1/W2 base, +17*k  (imm 136k bytes)
    const int rb2 = 17 * ghi + glo;        // R2/W3 base, +272*k (imm 2176k bytes)

    // ---- load: lane g holds amps (g<<4)|k, k=0..15 (64B contiguous) ----
    const float4* xb4 = (const float4*)(x + (size_t)b * NSTATE) + g * 4;
    f2 r[PER_T];
    #pragma unroll
    for (int c = 0; c < 4; ++c) {
        float4 v = xb4[c];
        r[4*c+0] = f2{v.x, 0.f};
        r[4*c+1] = f2{v.y, 0.f};
        r[4*c+2] = f2{v.z, 0.f};
        r[4*c+3] = f2{v.w, 0.f};
    }

    const int reps = reps_ptr[0];
    for (int rep = 0; rep < reps; ++rep) {
        #pragma unroll 1
        for (int l = 0; l < QDEPTH; ++l) {
            const f2* M = mats_g + l * WIRES * 8;   // wave-uniform -> s_load

            // Phase 1: wires 8..11 on local bits 3..0 (bit = 11-wire)
            gate<3>(r, M + 8*8);  gate<2>(r, M + 9*8);
            gate<1>(r, M + 10*8); gate<0>(r, M + 11*8);

            // W1: scatter canonical
            #pragma unroll
            for (int k = 0; k < PER_T; ++k) st[w1b + k] = r[k];
            __syncthreads();
            // R1: gather amp bits 7..4 local
            #pragma unroll
            for (int k = 0; k < PER_T; ++k) r[k] = st[rb1 + 17 * k];
            // no barrier: W2 rewrites exactly the slots this lane just read

            // Phase 2: wires 4..7
            gate<3>(r, M + 4*8); gate<2>(r, M + 5*8);
            gate<1>(r, M + 6*8); gate<0>(r, M + 7*8);

            #pragma unroll
            for (int k = 0; k < PER_T; ++k) st[rb1 + 17 * k] = r[k];
            __syncthreads();
            // R2: gather amp bits 11..8 local
            #pragma unroll
            for (int k = 0; k < PER_T; ++k) r[k] = st[rb2 + 272 * k];
            // no barrier: W3 rewrites exactly the slots this lane just read

            // Phase 3: wires 0..3
            gate<3>(r, M + 0*8); gate<2>(r, M + 1*8);
            gate<1>(r, M + 2*8); gate<0>(r, M + 3*8);

            #pragma unroll
            for (int k = 0; k < PER_T; ++k) st[rb2 + 272 * k] = r[k];
            __syncthreads();

            // R3: gather canonical ∘ F (CNOT ring). i = (g<<4)|k;
            // F(i) = XOR of COLS columns over set bits of i.
            int Fg = 0;
            #pragma unroll
            for (int j = 0; j < 8; ++j)
                Fg ^= ((g >> j) & 1) ? COLS.v[l][4 + j] : 0;
            const int c0 = COLS.v[l][0], c1 = COLS.v[l][1];
            const int c2 = COLS.v[l][2], c3 = COLS.v[l][3];
            #pragma unroll
            for (int k = 0; k < PER_T; ++k) {
                int ck = ((k & 1) ? c0 : 0) ^ ((k & 2) ? c1 : 0) ^
                         ((k & 4) ? c2 : 0) ^ ((k & 8) ? c3 : 0);
                r[k] = st[slotf(Fg ^ ck)];
            }
            __syncthreads();   // protect next layer's W1 scatter
            // r[k] = amp_after_layer[(g<<4)|k]  (canonical again)
        }
    }

    // ---- write out (r is canonical: 16 consecutive amps per lane) ----
    if (write_mode == 0) {
        // harness views complex output as float32 real part
        float4* ob4 = (float4*)(out + (size_t)b * NSTATE) + g * 4;
        #pragma unroll
        for (int c = 0; c < 4; ++c)
            ob4[c] = make_float4(r[4*c].x, r[4*c+1].x, r[4*c+2].x, r[4*c+3].x);
    } else {
        float4* ob4 = (float4*)((float2*)out + (size_t)b * NSTATE) + g * 8;
        #pragma unroll
        for (int k = 0; k < PER_T; k += 2)
            ob4[k >> 1] = make_float4(r[k].x, r[k].y, r[k+1].x, r[k+1].y);
    }
}

extern "C" void kernel_launch(void* const* d_in, const int* in_sizes, int n_in,
                              void* d_out, int out_size, void* d_ws, size_t ws_size,
                              hipStream_t stream) {
    const float* x    = (const float*)d_in[0];
    const float* wts  = (const float*)d_in[1];
    const int*   reps = (const int*)d_in[2];
    float*       out  = (float*)d_out;
    f2*          mg   = (f2*)d_ws;            // 96 gates * 8 f2 = 3 KB scratch
    (void)in_sizes; (void)n_in; (void)ws_size;

    const int write_mode = (out_size >= 2 * 1024 * NSTATE) ? 1 : 0;

    mats_kernel<<<1, 128, 0, stream>>>(wts, mg);
    qsim_kernel<<<1024, BLOCK, 0, stream>>>(x, mg, reps, out, write_mode);
}